// Round 7
// baseline (203.036 us; speedup 1.0000x reference)
//
#include <hip/hip_runtime.h>

#define BB 2
#define NN 16
#define LQ 512
#define DKk 64
#define DVv 64
#define DDd 128
#define H2 256
#define NEG_INF -1e9f
#define CAP 131072

// ---------------------------------------------------------------------------
// Stage 1 v2: 2 rows per block, grid 1024, 4 blocks/CU, 16 waves/CU.
// Per-(row,g) fp64 chain unchanged -> bit-identical U/W outputs.
// Block 0 thread 0 also zeroes the ambiguous-pair counter.
// ---------------------------------------------------------------------------
__global__ __launch_bounds__(256) void mlp_stage1(
    const float* __restrict__ d0, const float* __restrict__ d1,
    const float* __restrict__ W1, const float* __restrict__ b1,
    double* __restrict__ U64, double* __restrict__ W64,
    float* __restrict__ U32, float* __restrict__ W32,
    int* __restrict__ count)
{
    __shared__ float drow[2][DDd];
    int gid = blockIdx.x;            // half(2) x rowgroup(512)
    int half = gid >> 9;
    int r0 = (gid & 511) * 2;        // rows r0..r0+1 of 1024
    const float* din = half ? d1 : d0;
    int w1off = half ? DDd : 0;
    double* o64 = half ? W64 : U64;
    float* o32 = half ? W32 : U32;
    int t = threadIdx.x;
    if (gid == 0 && t == 0) *count = 0;
    drow[t >> 7][t & 127] = din[(size_t)(r0 + (t >> 7)) * DDd + (t & 127)];
    __syncthreads();
    int g = t;
    double acc[2] = {};
#pragma unroll 2
    for (int f = 0; f < DDd; f += 4) {
        double w0 = (double)W1[(w1off + f + 0) * H2 + g];
        double w1 = (double)W1[(w1off + f + 1) * H2 + g];
        double w2 = (double)W1[(w1off + f + 2) * H2 + g];
        double w3 = (double)W1[(w1off + f + 3) * H2 + g];
#pragma unroll
        for (int r = 0; r < 2; ++r) {
            float4 dr = *(const float4*)&drow[r][f];
            acc[r] = fma((double)dr.x, w0, acc[r]);
            acc[r] = fma((double)dr.y, w1, acc[r]);
            acc[r] = fma((double)dr.z, w2, acc[r]);
            acc[r] = fma((double)dr.w, w3, acc[r]);
        }
    }
    double bb = half ? 0.0 : (double)b1[g];
#pragma unroll
    for (int r = 0; r < 2; ++r) {
        double a = acc[r] + bb;
        o64[(size_t)(r0 + r) * H2 + g] = a;
        o32[(size_t)(r0 + r) * H2 + g] = (float)a;
    }
}

// ---------------------------------------------------------------------------
// dec_full v6: per-pair global atomic replaced by LDS aggregation + one
// global atomicAdd per block (R4: removed the 60-75 us same-line atomic
// serialization floor). Decision math untouched.
// ---------------------------------------------------------------------------
__global__ __launch_bounds__(256, 4) void dec_full(
    const float* __restrict__ U32, const float* __restrict__ W32,
    const float* __restrict__ W2, const float* __restrict__ b2,
    float* __restrict__ dec_out, int* __restrict__ count, int* __restrict__ list)
{
    __shared__ __align__(16) float Us[16][68];    // [i][g-chunk 64]
    __shared__ __align__(16) float Ws[32][68];    // [j][g-chunk 64]
    __shared__ __align__(16) float gvs[H2];
    __shared__ int lbuf[512];
    __shared__ int lcnt, lbase;
    int bid = blockIdx.x;            // b(2) x it(32) x jt(16)
    int b  = bid >> 9;
    int i0 = ((bid >> 4) & 31) * 16;
    int j0 = (bid & 15) * 32;
    int t = threadIdx.x;
    gvs[t] = W2[t * 2 + 1] - W2[t * 2];
    if (t == 0) lcnt = 0;
    float bias = b2[1] - b2[0];
    int ti = t >> 4, tj = t & 15;    // i = i0+ti; j in {j0+tj, j0+tj+16}
    float acc0 = 0.f, acc1 = 0.f;
    for (int gc = 0; gc < H2; gc += 64) {
        __syncthreads();
        {   // stage U: 16 rows x 16 float4, 1/thread, coalesced
            int ui = t >> 4, gq = t & 15;
            *(float4*)&Us[ui][gq * 4] =
                *(const float4*)(U32 + ((size_t)(b * LQ) + i0 + ui) * H2 + gc + gq * 4);
        }
        {   // stage W: 32 rows x 16 float4, 2/thread, coalesced
            int wj = t >> 3, gq = t & 7;
            const float* src = W32 + ((size_t)(b * LQ) + j0 + wj) * H2 + gc;
            *(float4*)&Ws[wj][gq * 4] = *(const float4*)(src + gq * 4);
            *(float4*)&Ws[wj][(gq + 8) * 4] = *(const float4*)(src + (gq + 8) * 4);
        }
        __syncthreads();
        float4 u_c  = *(const float4*)&Us[ti][0];
        float4 gv_c = *(const float4*)&gvs[gc];
        float4 wA_c = *(const float4*)&Ws[tj][0];
        float4 wB_c = *(const float4*)&Ws[tj + 16][0];
#pragma unroll 5
        for (int gg = 0; gg < 60; gg += 4) {
            float4 u_n  = *(const float4*)&Us[ti][gg + 4];
            float4 gv_n = *(const float4*)&gvs[gc + gg + 4];
            float4 wA_n = *(const float4*)&Ws[tj][gg + 4];
            float4 wB_n = *(const float4*)&Ws[tj + 16][gg + 4];
            acc0 = fmaf(fmaxf(u_c.x + wA_c.x, 0.f), gv_c.x, acc0);
            acc1 = fmaf(fmaxf(u_c.x + wB_c.x, 0.f), gv_c.x, acc1);
            acc0 = fmaf(fmaxf(u_c.y + wA_c.y, 0.f), gv_c.y, acc0);
            acc1 = fmaf(fmaxf(u_c.y + wB_c.y, 0.f), gv_c.y, acc1);
            acc0 = fmaf(fmaxf(u_c.z + wA_c.z, 0.f), gv_c.z, acc0);
            acc1 = fmaf(fmaxf(u_c.z + wB_c.z, 0.f), gv_c.z, acc1);
            acc0 = fmaf(fmaxf(u_c.w + wA_c.w, 0.f), gv_c.w, acc0);
            acc1 = fmaf(fmaxf(u_c.w + wB_c.w, 0.f), gv_c.w, acc1);
            u_c = u_n; gv_c = gv_n; wA_c = wA_n; wB_c = wB_n;
        }
        acc0 = fmaf(fmaxf(u_c.x + wA_c.x, 0.f), gv_c.x, acc0);
        acc1 = fmaf(fmaxf(u_c.x + wB_c.x, 0.f), gv_c.x, acc1);
        acc0 = fmaf(fmaxf(u_c.y + wA_c.y, 0.f), gv_c.y, acc0);
        acc1 = fmaf(fmaxf(u_c.y + wB_c.y, 0.f), gv_c.y, acc1);
        acc0 = fmaf(fmaxf(u_c.z + wA_c.z, 0.f), gv_c.z, acc0);
        acc1 = fmaf(fmaxf(u_c.z + wB_c.z, 0.f), gv_c.z, acc1);
        acc0 = fmaf(fmaxf(u_c.w + wA_c.w, 0.f), gv_c.w, acc0);
        acc1 = fmaf(fmaxf(u_c.w + wB_c.w, 0.f), gv_c.w, acc1);
    }
    int row = b * LQ + i0 + ti;
    float gA = acc0 + bias, gB = acc1 + bias;
    int jA = j0 + tj, jB = j0 + tj + 16;
    dec_out[(size_t)row * LQ + jA] = gA > 0.f ? 1.f : 0.f;
    dec_out[(size_t)row * LQ + jB] = gB > 0.f ? 1.f : 0.f;
    if (fabsf(gA) < 2e-2f) { int lx = atomicAdd(&lcnt, 1); lbuf[lx] = (row << 9) | jA; }
    if (fabsf(gB) < 2e-2f) { int lx = atomicAdd(&lcnt, 1); lbuf[lx] = (row << 9) | jB; }
    __syncthreads();
    if (t == 0 && lcnt > 0) lbase = atomicAdd(count, lcnt);
    __syncthreads();
    for (int x = t; x < lcnt; x += 256) {
        int ix = lbase + x;
        if (ix < CAP) list[ix] = lbuf[x];
    }
}

// ---------------------------------------------------------------------------
// Exact fp64 gap for every flagged pair; writes fp64-sign decision.
// ---------------------------------------------------------------------------
__global__ __launch_bounds__(256) void gap64_kernel(
    const double* __restrict__ U64, const double* __restrict__ W64,
    const float* __restrict__ W2, const float* __restrict__ b2,
    const int* __restrict__ count, const int* __restrict__ list,
    float* __restrict__ dec_out)
{
    int n = *count; if (n > CAP) n = CAP;
    int gw = (blockIdx.x * 256 + threadIdx.x) >> 6;
    int lane = threadIdx.x & 63;
    int nw = (gridDim.x * 256) >> 6;
    for (int idx = gw; idx < n; idx += nw) {
        int pij = list[idx];
        int j = pij & (LQ - 1);
        int row = pij >> 9;
        int b = row >> 9;
        const double* u = U64 + (size_t)row * H2;
        const double* w = W64 + ((size_t)(b * LQ) + j) * H2;
        double acc = 0.0;
        for (int g = lane; g < H2; g += 64) {
            double tv = u[g] + w[g];
            tv = tv > 0.0 ? tv : 0.0;
            acc = fma(tv, (double)W2[g * 2 + 1] - (double)W2[g * 2 + 0], acc);
        }
#pragma unroll
        for (int off = 32; off; off >>= 1) acc += __shfl_xor(acc, off, 64);
        if (lane == 0) {
            acc += (double)b2[1] - (double)b2[0];
            dec_out[(size_t)row * LQ + j] = acc > 0.0 ? 1.f : 0.f;
        }
    }
}

// ---------------------------------------------------------------------------
// Fused attention v4b: QK/softmax = v3 (balanced LDS/VALU); PV rebuilt.
// R5 post-mortem: PV was LDS-PIPE-saturated (per jj: 2 broadcast b128 + b32
// = ~14 pipe-cyc for only 8 FMA; ~29 us of the 59). v4 PV: P never touches
// LDS. After softmax, P[row][j] is wave-uniform per output row and lives in
// the owner lane's sA/sB regs -> v_readlane (uniform lane id cq*16+jq) to
// SGPR, used as the scalar FMA operand. Per jj: 1 spread ds_read_b32 of V
// (5.8 cyc) + 8 readlane + 8 FMA -> L=5.8 < V/4=8: VALU-bound.
// v4b fixes the R6 compile error: no ## pasting across member access
// (0.CC lexed as one pp-number); components passed as full expressions.
// PV accumulation order (j ascending per o[r]) identical to v3.
// ---------------------------------------------------------------------------
#define QK_R(ar, sa, sb)                                   \
    sa.x = fmaf(ar, b0.x, sa.x); sa.y = fmaf(ar, b0.y, sa.y); \
    sa.z = fmaf(ar, b0.z, sa.z); sa.w = fmaf(ar, b0.w, sa.w); \
    sb.x = fmaf(ar, b1.x, sb.x); sb.y = fmaf(ar, b1.y, sb.y); \
    sb.z = fmaf(ar, b1.z, sb.z); sb.w = fmaf(ar, b1.w, sb.w);

#define SM_ROW(sa, sb, r) {                                                     \
    size_t dro = ((size_t)(b * LQ) + i0 + ig * 8 + r) * LQ + lane * 4;          \
    float4 m0 = *(const float4*)&dec[dro];                                      \
    float4 m1 = *(const float4*)&dec[dro + 256];                                \
    sa.x = m0.x != 0.f ? sa.x * 0.125f : NEG_INF;                               \
    sa.y = m0.y != 0.f ? sa.y * 0.125f : NEG_INF;                               \
    sa.z = m0.z != 0.f ? sa.z * 0.125f : NEG_INF;                               \
    sa.w = m0.w != 0.f ? sa.w * 0.125f : NEG_INF;                               \
    sb.x = m1.x != 0.f ? sb.x * 0.125f : NEG_INF;                               \
    sb.y = m1.y != 0.f ? sb.y * 0.125f : NEG_INF;                               \
    sb.z = m1.z != 0.f ? sb.z * 0.125f : NEG_INF;                               \
    sb.w = m1.w != 0.f ? sb.w * 0.125f : NEG_INF;                               \
    float mx = fmaxf(fmaxf(fmaxf(sa.x, sa.y), fmaxf(sa.z, sa.w)),              \
                     fmaxf(fmaxf(sb.x, sb.y), fmaxf(sb.z, sb.w)));              \
    _Pragma("unroll")                                                            \
    for (int off = 1; off < 64; off <<= 1) mx = fmaxf(mx, __shfl_xor(mx, off, 64)); \
    sa.x = __expf(sa.x - mx); sa.y = __expf(sa.y - mx);                         \
    sa.z = __expf(sa.z - mx); sa.w = __expf(sa.w - mx);                         \
    sb.x = __expf(sb.x - mx); sb.y = __expf(sb.y - mx);                         \
    sb.z = __expf(sb.z - mx); sb.w = __expf(sb.w - mx);                         \
    float sm = sa.x + sa.y + sa.z + sa.w + sb.x + sb.y + sb.z + sb.w;           \
    _Pragma("unroll")                                                            \
    for (int off = 1; off < 64; off <<= 1) sm += __shfl_xor(sm, off, 64);       \
    float inv = 1.f / sm;                                                       \
    sa.x *= inv; sa.y *= inv; sa.z *= inv; sa.w *= inv;                         \
    sb.x *= inv; sb.y *= inv; sb.z *= inv; sb.w *= inv;                         \
    size_t aro = ((size_t)bn * LQ + i0 + ig * 8 + r) * LQ + lane * 4;           \
    *(float4*)&attn[aro] = sa;                                                  \
    *(float4*)&attn[aro + 256] = sb;                                            \
}

// one (jq, component) PV step: broadcast P[row][j] from owner lane, FMA with V
#define RL(x) __int_as_float(__builtin_amdgcn_readlane(__float_as_int(x), lsrc))
#define PV_STEP(p0, p1, p2, p3, p4, p5, p6, p7, ccoff) {                        \
    float vv = Vs[(jq * 4 + (ccoff)) * 68 + lane];                              \
    o[0] = fmaf(RL(p0), vv, o[0]); o[1] = fmaf(RL(p1), vv, o[1]);               \
    o[2] = fmaf(RL(p2), vv, o[2]); o[3] = fmaf(RL(p3), vv, o[3]);               \
    o[4] = fmaf(RL(p4), vv, o[4]); o[5] = fmaf(RL(p5), vv, o[5]);               \
    o[6] = fmaf(RL(p6), vv, o[6]); o[7] = fmaf(RL(p7), vv, o[7]);               \
}

__global__ __launch_bounds__(256) void fused_attn(
    const float* __restrict__ q, const float* __restrict__ k,
    const float* __restrict__ v, const float* __restrict__ dec,
    float* __restrict__ attn, float* __restrict__ out)
{
    __shared__ __align__(16) float smem[10560];   // 42.2 KB, phase-overlaid
    float* qT = smem;            // [64 kk][36]      (QK phase)
    float* kT = smem + 2304;     // [16 kk][516]     (QK phase, per chunk)
    float* Vs = smem;            // [64 j][68]       (PV phase)
    int bid = blockIdx.x;
    int bn = bid >> 4;
    int i0 = (bid & 15) * 32;
    int b = bn >> 4;
    int t = threadIdx.x;
    int ig = t >> 6;             // wave id: i-rows i0 + ig*8 + (0..7)
    int lane = t & 63;           // j-quads {4*lane, 256+4*lane}; PV: d = lane

    {   // stage qT (transpose): i = t>>3 (0..31), kkq = (t&7)+8*it
        int qi = t >> 3;
        const float* src = q + ((size_t)bn * LQ + i0 + qi) * DKk;
#pragma unroll
        for (int it = 0; it < 2; ++it) {
            int kkq = (t & 7) + it * 8;
            float4 t4 = *(const float4*)(src + kkq * 4);
            qT[(kkq * 4 + 0) * 36 + qi] = t4.x;
            qT[(kkq * 4 + 1) * 36 + qi] = t4.y;
            qT[(kkq * 4 + 2) * 36 + qi] = t4.z;
            qT[(kkq * 4 + 3) * 36 + qi] = t4.w;
        }
    }

    float4 sA0 = {}, sA1 = {}, sA2 = {}, sA3 = {}, sA4 = {}, sA5 = {}, sA6 = {}, sA7 = {};
    float4 sB0 = {}, sB1 = {}, sB2 = {}, sB3 = {}, sB4 = {}, sB5 = {}, sB6 = {}, sB7 = {};

    for (int kc = 0; kc < 4; ++kc) {
        __syncthreads();
        {   // stage kT chunk: 16 kk x 512 j, transposed. q = t&3, j = (t>>2)+64*it
            int qq = t & 3;
            int jb = t >> 2;
#pragma unroll
            for (int it = 0; it < 8; ++it) {
                int j = jb + it * 64;
                float4 t4 = *(const float4*)(k + ((size_t)bn * LQ + j) * DKk + kc * 16 + qq * 4);
                kT[(qq * 4 + 0) * 516 + j] = t4.x;
                kT[(qq * 4 + 1) * 516 + j] = t4.y;
                kT[(qq * 4 + 2) * 516 + j] = t4.z;
                kT[(qq * 4 + 3) * 516 + j] = t4.w;
            }
        }
        __syncthreads();
#pragma unroll
        for (int kk = 0; kk < 16; ++kk) {
            float4 a0 = *(const float4*)&qT[(kc * 16 + kk) * 36 + ig * 8];
            float4 a1 = *(const float4*)&qT[(kc * 16 + kk) * 36 + ig * 8 + 4];
            float4 b0 = *(const float4*)&kT[kk * 516 + lane * 4];
            float4 b1 = *(const float4*)&kT[kk * 516 + 256 + lane * 4];
            QK_R(a0.x, sA0, sB0); QK_R(a0.y, sA1, sB1);
            QK_R(a0.z, sA2, sB2); QK_R(a0.w, sA3, sB3);
            QK_R(a1.x, sA4, sB4); QK_R(a1.y, sA5, sB5);
            QK_R(a1.z, sA6, sB6); QK_R(a1.w, sA7, sB7);
        }
    }

    // mask + softmax (width-64, rows fully in-wave) + attn write
    SM_ROW(sA0, sB0, 0); SM_ROW(sA1, sB1, 1); SM_ROW(sA2, sB2, 2); SM_ROW(sA3, sB3, 3);
    SM_ROW(sA4, sB4, 4); SM_ROW(sA5, sB5, 5); SM_ROW(sA6, sB6, 6); SM_ROW(sA7, sB7, 7);

    // ---- PV: P in registers (readlane broadcast), V staged per 64-j chunk ----
    float o[8] = {};
#pragma unroll
    for (int cq = 0; cq < 4; ++cq) {         // j = cq*64 + jq*4 + cc  (sA half)
        __syncthreads();
        {   // stage Vs: j = t>>2, dq = (t&3)+4*it
            int vj = t >> 2;
#pragma unroll
            for (int it = 0; it < 4; ++it) {
                int dq = (t & 3) + it * 4;
                *(float4*)&Vs[vj * 68 + dq * 4] =
                    *(const float4*)(v + ((size_t)bn * LQ + cq * 64 + vj) * DVv + dq * 4);
            }
        }
        __syncthreads();
        for (int jq = 0; jq < 16; ++jq) {    // uniform loop, lsrc in SGPR
            int lsrc = cq * 16 + jq;
            PV_STEP(sA0.x, sA1.x, sA2.x, sA3.x, sA4.x, sA5.x, sA6.x, sA7.x, 0);
            PV_STEP(sA0.y, sA1.y, sA2.y, sA3.y, sA4.y, sA5.y, sA6.y, sA7.y, 1);
            PV_STEP(sA0.z, sA1.z, sA2.z, sA3.z, sA4.z, sA5.z, sA6.z, sA7.z, 2);
            PV_STEP(sA0.w, sA1.w, sA2.w, sA3.w, sA4.w, sA5.w, sA6.w, sA7.w, 3);
        }
    }
#pragma unroll
    for (int cq = 0; cq < 4; ++cq) {         // j = 256 + cq*64 + jq*4 + cc (sB half)
        __syncthreads();
        {
            int vj = t >> 2;
#pragma unroll
            for (int it = 0; it < 4; ++it) {
                int dq = (t & 3) + it * 4;
                *(float4*)&Vs[vj * 68 + dq * 4] =
                    *(const float4*)(v + ((size_t)bn * LQ + 256 + cq * 64 + vj) * DVv + dq * 4);
            }
        }
        __syncthreads();
        for (int jq = 0; jq < 16; ++jq) {
            int lsrc = cq * 16 + jq;
            PV_STEP(sB0.x, sB1.x, sB2.x, sB3.x, sB4.x, sB5.x, sB6.x, sB7.x, 0);
            PV_STEP(sB0.y, sB1.y, sB2.y, sB3.y, sB4.y, sB5.y, sB6.y, sB7.y, 1);
            PV_STEP(sB0.z, sB1.z, sB2.z, sB3.z, sB4.z, sB5.z, sB6.z, sB7.z, 2);
            PV_STEP(sB0.w, sB1.w, sB2.w, sB3.w, sB4.w, sB5.w, sB6.w, sB7.w, 3);
        }
    }
#pragma unroll
    for (int r = 0; r < 8; ++r)
        out[((size_t)bn * LQ + i0 + ig * 8 + r) * DVv + lane] = o[r];
}

// ---------------------------------------------------------------------------
extern "C" void kernel_launch(void* const* d_in, const int* in_sizes, int n_in,
                              void* d_out, int out_size, void* d_ws, size_t ws_size,
                              hipStream_t stream)
{
    const float* q  = (const float*)d_in[0];
    const float* k  = (const float*)d_in[1];
    const float* v  = (const float*)d_in[2];
    const float* d0 = (const float*)d_in[3];
    const float* d1 = (const float*)d_in[4];
    const float* W1 = (const float*)d_in[5];
    const float* b1 = (const float*)d_in[6];
    const float* W2 = (const float*)d_in[7];
    const float* b2 = (const float*)d_in[8];

    float* out  = (float*)d_out;                                  // [2,16,512,64]
    float* attn = out + (size_t)BB * NN * LQ * DVv;               // [2,16,512,512]
    float* dec  = attn + (size_t)BB * NN * LQ * LQ;               // [2,1,512,512]

    // Scratch inside the attn region (32 MB); fully consumed before
    // fused_attn overwrites every attn element (same stream => ordered).
    char* scratch = (char*)attn;
    double* U64 = (double*)(scratch);                             // 0..2 MB
    double* W64 = (double*)(scratch + (2u << 20));                // 2..4 MB
    float*  U32 = (float*) (scratch + (4u << 20));                // 4..5 MB
    float*  W32 = (float*) (scratch + (5u << 20));                // 5..6 MB
    int* count  = (int*)   (scratch + (6u << 20));                // 4 B
    int* list   = (int*)   (scratch + (6u << 20) + 4096);         // 512 KB

    mlp_stage1<<<1024, 256, 0, stream>>>(d0, d1, W1, b1, U64, W64, U32, W32, count);
    dec_full<<<1024, 256, 0, stream>>>(U32, W32, W2, b2, dec, count, list);
    gap64_kernel<<<256, 256, 0, stream>>>(U64, W64, W2, b2, count, list, dec);
    fused_attn<<<512, 256, 0, stream>>>(q, k, v, dec, attn, out);
}

// Round 8
// 178.114 us; speedup vs baseline: 1.1399x; 1.1399x over previous
//
#include <hip/hip_runtime.h>

#define BB 2
#define NN 16
#define LQ 512
#define DKk 64
#define DVv 64
#define DDd 128
#define H2 256
#define NEG_INF -1e9f

// ---------------------------------------------------------------------------
// Stage 1 v2: 2 rows per block, grid 1024, 4 blocks/CU, 16 waves/CU.
// Per-(row,g) fp64 chain unchanged -> bit-identical U/W outputs.
// ---------------------------------------------------------------------------
__global__ __launch_bounds__(256) void mlp_stage1(
    const float* __restrict__ d0, const float* __restrict__ d1,
    const float* __restrict__ W1, const float* __restrict__ b1,
    double* __restrict__ U64, double* __restrict__ W64,
    float* __restrict__ U32, float* __restrict__ W32)
{
    __shared__ float drow[2][DDd];
    int gid = blockIdx.x;            // half(2) x rowgroup(512)
    int half = gid >> 9;
    int r0 = (gid & 511) * 2;        // rows r0..r0+1 of 1024
    const float* din = half ? d1 : d0;
    int w1off = half ? DDd : 0;
    double* o64 = half ? W64 : U64;
    float* o32 = half ? W32 : U32;
    int t = threadIdx.x;
    drow[t >> 7][t & 127] = din[(size_t)(r0 + (t >> 7)) * DDd + (t & 127)];
    __syncthreads();
    int g = t;
    double acc[2] = {};
#pragma unroll 2
    for (int f = 0; f < DDd; f += 4) {
        double w0 = (double)W1[(w1off + f + 0) * H2 + g];
        double w1 = (double)W1[(w1off + f + 1) * H2 + g];
        double w2 = (double)W1[(w1off + f + 2) * H2 + g];
        double w3 = (double)W1[(w1off + f + 3) * H2 + g];
#pragma unroll
        for (int r = 0; r < 2; ++r) {
            float4 dr = *(const float4*)&drow[r][f];
            acc[r] = fma((double)dr.x, w0, acc[r]);
            acc[r] = fma((double)dr.y, w1, acc[r]);
            acc[r] = fma((double)dr.z, w2, acc[r]);
            acc[r] = fma((double)dr.w, w3, acc[r]);
        }
    }
    double bb = half ? 0.0 : (double)b1[g];
#pragma unroll
    for (int r = 0; r < 2; ++r) {
        double a = acc[r] + bb;
        o64[(size_t)(r0 + r) * H2 + g] = a;
        o32[(size_t)(r0 + r) * H2 + g] = (float)a;
    }
}

// ---------------------------------------------------------------------------
// dec_full v7: fp32 bulk decisions + IN-BLOCK fp64 re-evaluation of the
// ambiguous band (|gap| < 2e-2). The flagged pairs live in this block's LDS
// lbuf; the 4 waves re-evaluate them cooperatively with EXACTLY gap64's
// loop & reduce order -> bit-identical decisions. Removes the gap64
// dispatch, the global count/list round-trip, and the last global atomic.
// ---------------------------------------------------------------------------
__global__ __launch_bounds__(256, 4) void dec_full(
    const float* __restrict__ U32, const float* __restrict__ W32,
    const double* __restrict__ U64, const double* __restrict__ W64,
    const float* __restrict__ W2, const float* __restrict__ b2,
    float* __restrict__ dec_out)
{
    __shared__ __align__(16) float Us[16][68];    // [i][g-chunk 64]
    __shared__ __align__(16) float Ws[32][68];    // [j][g-chunk 64]
    __shared__ __align__(16) float gvs[H2];
    __shared__ int lbuf[512];
    __shared__ int lcnt;
    int bid = blockIdx.x;            // b(2) x it(32) x jt(16)
    int b  = bid >> 9;
    int i0 = ((bid >> 4) & 31) * 16;
    int j0 = (bid & 15) * 32;
    int t = threadIdx.x;
    gvs[t] = W2[t * 2 + 1] - W2[t * 2];
    if (t == 0) lcnt = 0;
    float bias = b2[1] - b2[0];
    int ti = t >> 4, tj = t & 15;    // i = i0+ti; j in {j0+tj, j0+tj+16}
    float acc0 = 0.f, acc1 = 0.f;
    for (int gc = 0; gc < H2; gc += 64) {
        __syncthreads();
        {   // stage U: 16 rows x 16 float4, 1/thread, coalesced
            int ui = t >> 4, gq = t & 15;
            *(float4*)&Us[ui][gq * 4] =
                *(const float4*)(U32 + ((size_t)(b * LQ) + i0 + ui) * H2 + gc + gq * 4);
        }
        {   // stage W: 32 rows x 16 float4, 2/thread, coalesced
            int wj = t >> 3, gq = t & 7;
            const float* src = W32 + ((size_t)(b * LQ) + j0 + wj) * H2 + gc;
            *(float4*)&Ws[wj][gq * 4] = *(const float4*)(src + gq * 4);
            *(float4*)&Ws[wj][(gq + 8) * 4] = *(const float4*)(src + (gq + 8) * 4);
        }
        __syncthreads();
        float4 u_c  = *(const float4*)&Us[ti][0];
        float4 gv_c = *(const float4*)&gvs[gc];
        float4 wA_c = *(const float4*)&Ws[tj][0];
        float4 wB_c = *(const float4*)&Ws[tj + 16][0];
#pragma unroll 5
        for (int gg = 0; gg < 60; gg += 4) {
            float4 u_n  = *(const float4*)&Us[ti][gg + 4];
            float4 gv_n = *(const float4*)&gvs[gc + gg + 4];
            float4 wA_n = *(const float4*)&Ws[tj][gg + 4];
            float4 wB_n = *(const float4*)&Ws[tj + 16][gg + 4];
            acc0 = fmaf(fmaxf(u_c.x + wA_c.x, 0.f), gv_c.x, acc0);
            acc1 = fmaf(fmaxf(u_c.x + wB_c.x, 0.f), gv_c.x, acc1);
            acc0 = fmaf(fmaxf(u_c.y + wA_c.y, 0.f), gv_c.y, acc0);
            acc1 = fmaf(fmaxf(u_c.y + wB_c.y, 0.f), gv_c.y, acc1);
            acc0 = fmaf(fmaxf(u_c.z + wA_c.z, 0.f), gv_c.z, acc0);
            acc1 = fmaf(fmaxf(u_c.z + wB_c.z, 0.f), gv_c.z, acc1);
            acc0 = fmaf(fmaxf(u_c.w + wA_c.w, 0.f), gv_c.w, acc0);
            acc1 = fmaf(fmaxf(u_c.w + wB_c.w, 0.f), gv_c.w, acc1);
            u_c = u_n; gv_c = gv_n; wA_c = wA_n; wB_c = wB_n;
        }
        acc0 = fmaf(fmaxf(u_c.x + wA_c.x, 0.f), gv_c.x, acc0);
        acc1 = fmaf(fmaxf(u_c.x + wB_c.x, 0.f), gv_c.x, acc1);
        acc0 = fmaf(fmaxf(u_c.y + wA_c.y, 0.f), gv_c.y, acc0);
        acc1 = fmaf(fmaxf(u_c.y + wB_c.y, 0.f), gv_c.y, acc1);
        acc0 = fmaf(fmaxf(u_c.z + wA_c.z, 0.f), gv_c.z, acc0);
        acc1 = fmaf(fmaxf(u_c.z + wB_c.z, 0.f), gv_c.z, acc1);
        acc0 = fmaf(fmaxf(u_c.w + wA_c.w, 0.f), gv_c.w, acc0);
        acc1 = fmaf(fmaxf(u_c.w + wB_c.w, 0.f), gv_c.w, acc1);
    }
    int row = b * LQ + i0 + ti;
    float gA = acc0 + bias, gB = acc1 + bias;
    int jA = j0 + tj, jB = j0 + tj + 16;
    dec_out[(size_t)row * LQ + jA] = gA > 0.f ? 1.f : 0.f;
    dec_out[(size_t)row * LQ + jB] = gB > 0.f ? 1.f : 0.f;
    if (fabsf(gA) < 2e-2f) { int lx = atomicAdd(&lcnt, 1); lbuf[lx] = (row << 9) | jA; }
    if (fabsf(gB) < 2e-2f) { int lx = atomicAdd(&lcnt, 1); lbuf[lx] = (row << 9) | jB; }
    __syncthreads();
    // ---- in-block fp64 re-eval (gap64's exact math/order), wave per pair ----
    int nloc = lcnt;
    int wv = t >> 6, ln = t & 63;
    for (int x = wv; x < nloc; x += 4) {
        int pij = lbuf[x];
        int j = pij & (LQ - 1);
        int prow = pij >> 9;
        int pb = prow >> 9;
        const double* u = U64 + (size_t)prow * H2;
        const double* w = W64 + ((size_t)(pb * LQ) + j) * H2;
        double acc = 0.0;
        for (int g = ln; g < H2; g += 64) {
            double tv = u[g] + w[g];
            tv = tv > 0.0 ? tv : 0.0;
            acc = fma(tv, (double)W2[g * 2 + 1] - (double)W2[g * 2 + 0], acc);
        }
#pragma unroll
        for (int off = 32; off; off >>= 1) acc += __shfl_xor(acc, off, 64);
        if (ln == 0) {
            acc += (double)b2[1] - (double)b2[0];
            dec_out[(size_t)prow * LQ + j] = acc > 0.0 ? 1.f : 0.f;
        }
    }
}

// ---------------------------------------------------------------------------
// Fused attention v5: QK/softmax/attn-write = proven R4-v2 code (bit-identical
// attn). PV rebuilt for LDS amortization: R7 post-mortem killed readlane-P
// (VGPR 216); R5 established PV is LDS-pipe-bound. New PV: wave = one 8-row
// i-oct, lane = jq(4) x dq(16); per step 1 full V-b128 + 2 Pt-b128 (4-addr
// multicast) feed 32 FMA -> L/F 2.75 -> 1.125. Pt[64][36] j-major transposed
// P (staged per 64-chunk by owner lanes); Vs[64][72]. Cross-jq partials
// reduced with 2 shfl_xor; lanes jq==0 write out. PV j-order interleaved
// (tolerance-checked output, not bit-exact path).
// ---------------------------------------------------------------------------
#define PV5R(pp, rr)                                                       \
    o[rr][0] = fmaf(pp, v4.x, o[rr][0]); o[rr][1] = fmaf(pp, v4.y, o[rr][1]); \
    o[rr][2] = fmaf(pp, v4.z, o[rr][2]); o[rr][3] = fmaf(pp, v4.w, o[rr][3]);

__global__ __launch_bounds__(256) void fused_attn(
    const float* __restrict__ q, const float* __restrict__ k,
    const float* __restrict__ v, const float* __restrict__ dec,
    float* __restrict__ attn, float* __restrict__ out)
{
    __shared__ __align__(16) float smem[10752];   // 43 KB, phase-overlaid
    float* qT = smem;            // [64][36]   kk-major  (QK phase)
    float* kT = smem + 2304;     // [64][132]  kk-major  (QK phase)
    float* Pt = smem;            // [64][36]   j-major   (PV phase)
    float* Vs = smem + 2304;     // [64][72]   j-major   (PV phase)
    int bid = blockIdx.x;
    int bn = bid >> 4;
    int i0 = (bid & 15) * 32;
    int b = bn >> 4;
    int t = threadIdx.x;

    {   // stage qT (transpose): i = t>>3, kkq = (t&7)+8*it
        int qi = t >> 3;
        const float* src = q + ((size_t)bn * LQ + i0 + qi) * DKk;
#pragma unroll
        for (int it = 0; it < 2; ++it) {
            int kkq = (t & 7) + it * 8;
            float4 t4 = *(const float4*)(src + kkq * 4);
            qT[(kkq * 4 + 0) * 36 + qi] = t4.x;
            qT[(kkq * 4 + 1) * 36 + qi] = t4.y;
            qT[(kkq * 4 + 2) * 36 + qi] = t4.z;
            qT[(kkq * 4 + 3) * 36 + qi] = t4.w;
        }
    }
    int tiq = t >> 5;            // 0..7  -> i = tiq*4 + r
    int tjq = t & 31;            // 0..31 -> j = c*128 + tjq*4 + cc
    float s[4][4][4];

#pragma unroll
    for (int c = 0; c < 4; ++c) {
        __syncthreads();
        {   // stage kT (transpose): j = (t>>2)+(it&1)*64, kkq = (t&3)+(it>>1)*4
            int kj = t >> 2;
#pragma unroll
            for (int it = 0; it < 8; ++it) {
                int jj = kj + (it & 1) * 64;
                int kkq = (t & 3) + (it >> 1) * 4;
                float4 t4 = *(const float4*)(k + ((size_t)bn * LQ + c * 128 + jj) * DKk + kkq * 4);
                kT[(kkq * 4 + 0) * 132 + jj] = t4.x;
                kT[(kkq * 4 + 1) * 132 + jj] = t4.y;
                kT[(kkq * 4 + 2) * 132 + jj] = t4.z;
                kT[(kkq * 4 + 3) * 132 + jj] = t4.w;
            }
        }
        __syncthreads();
        float acc[4][4] = {};
#pragma unroll 8
        for (int kk = 0; kk < 64; ++kk) {
            float4 a  = *(const float4*)&qT[kk * 36 + tiq * 4];
            float4 bb = *(const float4*)&kT[kk * 132 + tjq * 4];
            acc[0][0] = fmaf(a.x, bb.x, acc[0][0]); acc[0][1] = fmaf(a.x, bb.y, acc[0][1]);
            acc[0][2] = fmaf(a.x, bb.z, acc[0][2]); acc[0][3] = fmaf(a.x, bb.w, acc[0][3]);
            acc[1][0] = fmaf(a.y, bb.x, acc[1][0]); acc[1][1] = fmaf(a.y, bb.y, acc[1][1]);
            acc[1][2] = fmaf(a.y, bb.z, acc[1][2]); acc[1][3] = fmaf(a.y, bb.w, acc[1][3]);
            acc[2][0] = fmaf(a.z, bb.x, acc[2][0]); acc[2][1] = fmaf(a.z, bb.y, acc[2][1]);
            acc[2][2] = fmaf(a.z, bb.z, acc[2][2]); acc[2][3] = fmaf(a.z, bb.w, acc[2][3]);
            acc[3][0] = fmaf(a.w, bb.x, acc[3][0]); acc[3][1] = fmaf(a.w, bb.y, acc[3][1]);
            acc[3][2] = fmaf(a.w, bb.z, acc[3][2]); acc[3][3] = fmaf(a.w, bb.w, acc[3][3]);
        }
#pragma unroll
        for (int r = 0; r < 4; ++r) {
            float4 m4 = *(const float4*)&dec[((size_t)(b * LQ) + i0 + tiq * 4 + r) * LQ + c * 128 + tjq * 4];
            s[c][r][0] = m4.x != 0.f ? acc[r][0] * 0.125f : NEG_INF;
            s[c][r][1] = m4.y != 0.f ? acc[r][1] * 0.125f : NEG_INF;
            s[c][r][2] = m4.z != 0.f ? acc[r][2] * 0.125f : NEG_INF;
            s[c][r][3] = m4.w != 0.f ? acc[r][3] * 0.125f : NEG_INF;
        }
    }
    // softmax over 512 j per row (width-32 shuffle groups = tjq)
#pragma unroll
    for (int r = 0; r < 4; ++r) {
        float m = NEG_INF;
#pragma unroll
        for (int c = 0; c < 4; ++c)
#pragma unroll
            for (int cc = 0; cc < 4; ++cc) m = fmaxf(m, s[c][r][cc]);
#pragma unroll
        for (int off = 1; off < 32; off <<= 1) m = fmaxf(m, __shfl_xor(m, off, 32));
        float sum = 0.f;
#pragma unroll
        for (int c = 0; c < 4; ++c)
#pragma unroll
            for (int cc = 0; cc < 4; ++cc) {
                float e = __expf(s[c][r][cc] - m);
                s[c][r][cc] = e; sum += e;
            }
#pragma unroll
        for (int off = 1; off < 32; off <<= 1) sum += __shfl_xor(sum, off, 32);
        float inv = 1.f / sum;
#pragma unroll
        for (int c = 0; c < 4; ++c)
#pragma unroll
            for (int cc = 0; cc < 4; ++cc) s[c][r][cc] *= inv;
    }
#pragma unroll
    for (int c = 0; c < 4; ++c)
#pragma unroll
        for (int r = 0; r < 4; ++r) {
            float4 wv = make_float4(s[c][r][0], s[c][r][1], s[c][r][2], s[c][r][3]);
            *(float4*)&attn[((size_t)bn * LQ + i0 + tiq * 4 + r) * LQ + c * 128 + tjq * 4] = wv;
        }

    // ---- PV v5 over eight 64-j chunks: wave = i-oct, lane = jq(4) x dq(16) ----
    int oct = t >> 6;            // wave: i rows i0 + oct*8 + (0..7)
    int lane = t & 63;
    int jq = lane >> 4;          // j-quarter within chunk: jj = jq*16 + s16
    int dq = lane & 15;          // d = dq*4 .. +3
    float o[8][4] = {};
#pragma unroll
    for (int c8 = 0; c8 < 8; ++c8) {
        __syncthreads();
        if ((tjq >> 4) == (c8 & 1)) {      // owner lanes stage transposed P
            int jl = tjq & 15;             // jj = jl*4 + cc
            int c = c8 >> 1;
            *(float4*)&Pt[(jl * 4 + 0) * 36 + tiq * 4] =
                make_float4(s[c][0][0], s[c][1][0], s[c][2][0], s[c][3][0]);
            *(float4*)&Pt[(jl * 4 + 1) * 36 + tiq * 4] =
                make_float4(s[c][0][1], s[c][1][1], s[c][2][1], s[c][3][1]);
            *(float4*)&Pt[(jl * 4 + 2) * 36 + tiq * 4] =
                make_float4(s[c][0][2], s[c][1][2], s[c][2][2], s[c][3][2]);
            *(float4*)&Pt[(jl * 4 + 3) * 36 + tiq * 4] =
                make_float4(s[c][0][3], s[c][1][3], s[c][2][3], s[c][3][3]);
        }
        {   // stage Vs: j = t>>2, dq-slot = (t&3)+4*it
            int vj = t >> 2;
#pragma unroll
            for (int it = 0; it < 4; ++it) {
                int dqs = (t & 3) + it * 4;
                *(float4*)&Vs[vj * 72 + dqs * 4] =
                    *(const float4*)(v + ((size_t)bn * LQ + c8 * 64 + vj) * DVv + dqs * 4);
            }
        }
        __syncthreads();
#pragma unroll
        for (int s16 = 0; s16 < 16; ++s16) {
            int jj = jq * 16 + s16;
            float4 v4 = *(const float4*)&Vs[jj * 72 + dq * 4];
            float4 pl = *(const float4*)&Pt[jj * 36 + oct * 8];
            float4 ph = *(const float4*)&Pt[jj * 36 + oct * 8 + 4];
            PV5R(pl.x, 0) PV5R(pl.y, 1) PV5R(pl.z, 2) PV5R(pl.w, 3)
            PV5R(ph.x, 4) PV5R(ph.y, 5) PV5R(ph.z, 6) PV5R(ph.w, 7)
        }
    }
    // reduce the 4 j-quarter partials (lanes dq, dq+16, dq+32, dq+48)
#pragma unroll
    for (int r = 0; r < 8; ++r)
#pragma unroll
        for (int d = 0; d < 4; ++d) {
            o[r][d] += __shfl_xor(o[r][d], 16, 64);
            o[r][d] += __shfl_xor(o[r][d], 32, 64);
        }
    if (jq == 0) {
#pragma unroll
        for (int r = 0; r < 8; ++r)
            *(float4*)&out[((size_t)bn * LQ + i0 + oct * 8 + r) * DVv + dq * 4] =
                make_float4(o[r][0], o[r][1], o[r][2], o[r][3]);
    }
}

// ---------------------------------------------------------------------------
extern "C" void kernel_launch(void* const* d_in, const int* in_sizes, int n_in,
                              void* d_out, int out_size, void* d_ws, size_t ws_size,
                              hipStream_t stream)
{
    const float* q  = (const float*)d_in[0];
    const float* k  = (const float*)d_in[1];
    const float* v  = (const float*)d_in[2];
    const float* d0 = (const float*)d_in[3];
    const float* d1 = (const float*)d_in[4];
    const float* W1 = (const float*)d_in[5];
    const float* b1 = (const float*)d_in[6];
    const float* W2 = (const float*)d_in[7];
    const float* b2 = (const float*)d_in[8];

    float* out  = (float*)d_out;                                  // [2,16,512,64]
    float* attn = out + (size_t)BB * NN * LQ * DVv;               // [2,16,512,512]
    float* dec  = attn + (size_t)BB * NN * LQ * LQ;               // [2,1,512,512]

    // Scratch inside the attn region (32 MB); fully consumed before
    // fused_attn overwrites every attn element (same stream => ordered).
    char* scratch = (char*)attn;
    double* U64 = (double*)(scratch);                             // 0..2 MB
    double* W64 = (double*)(scratch + (2u << 20));                // 2..4 MB
    float*  U32 = (float*) (scratch + (4u << 20));                // 4..5 MB
    float*  W32 = (float*) (scratch + (5u << 20));                // 5..6 MB

    mlp_stage1<<<1024, 256, 0, stream>>>(d0, d1, W1, b1, U64, W64, U32, W32);
    dec_full<<<1024, 256, 0, stream>>>(U32, W32, U64, W64, W2, b2, dec);
    fused_attn<<<512, 256, 0, stream>>>(q, k, v, dec, attn, out);
}

// Round 9
// 156.038 us; speedup vs baseline: 1.3012x; 1.1415x over previous
//
#include <hip/hip_runtime.h>

#define BB 2
#define NN 16
#define LQ 512
#define DKk 64
#define DVv 64
#define DDd 128
#define H2 256
#define NEG_INF -1e9f

// ---------------------------------------------------------------------------
// Stage 1 v2: 2 rows per block, grid 1024, 4 blocks/CU, 16 waves/CU.
// Per-(row,g) fp64 chain unchanged -> bit-identical U/W outputs.
// ---------------------------------------------------------------------------
__global__ __launch_bounds__(256) void mlp_stage1(
    const float* __restrict__ d0, const float* __restrict__ d1,
    const float* __restrict__ W1, const float* __restrict__ b1,
    double* __restrict__ U64, double* __restrict__ W64,
    float* __restrict__ U32, float* __restrict__ W32)
{
    __shared__ float drow[2][DDd];
    int gid = blockIdx.x;            // half(2) x rowgroup(512)
    int half = gid >> 9;
    int r0 = (gid & 511) * 2;        // rows r0..r0+1 of 1024
    const float* din = half ? d1 : d0;
    int w1off = half ? DDd : 0;
    double* o64 = half ? W64 : U64;
    float* o32 = half ? W32 : U32;
    int t = threadIdx.x;
    drow[t >> 7][t & 127] = din[(size_t)(r0 + (t >> 7)) * DDd + (t & 127)];
    __syncthreads();
    int g = t;
    double acc[2] = {};
#pragma unroll 2
    for (int f = 0; f < DDd; f += 4) {
        double w0 = (double)W1[(w1off + f + 0) * H2 + g];
        double w1 = (double)W1[(w1off + f + 1) * H2 + g];
        double w2 = (double)W1[(w1off + f + 2) * H2 + g];
        double w3 = (double)W1[(w1off + f + 3) * H2 + g];
#pragma unroll
        for (int r = 0; r < 2; ++r) {
            float4 dr = *(const float4*)&drow[r][f];
            acc[r] = fma((double)dr.x, w0, acc[r]);
            acc[r] = fma((double)dr.y, w1, acc[r]);
            acc[r] = fma((double)dr.z, w2, acc[r]);
            acc[r] = fma((double)dr.w, w3, acc[r]);
        }
    }
    double bb = half ? 0.0 : (double)b1[g];
#pragma unroll
    for (int r = 0; r < 2; ++r) {
        double a = acc[r] + bb;
        o64[(size_t)(r0 + r) * H2 + g] = a;
        o32[(size_t)(r0 + r) * H2 + g] = (float)a;
    }
}

// ---------------------------------------------------------------------------
// dec_full v7 (proven R8): fp32 bulk decisions + IN-BLOCK fp64 re-eval of the
// ambiguous band (|gap| < 2e-2) with gap64's exact loop & reduce order ->
// bit-identical decisions. No global atomics, no extra dispatch.
// ---------------------------------------------------------------------------
__global__ __launch_bounds__(256, 4) void dec_full(
    const float* __restrict__ U32, const float* __restrict__ W32,
    const double* __restrict__ U64, const double* __restrict__ W64,
    const float* __restrict__ W2, const float* __restrict__ b2,
    float* __restrict__ dec_out)
{
    __shared__ __align__(16) float Us[16][68];    // [i][g-chunk 64]
    __shared__ __align__(16) float Ws[32][68];    // [j][g-chunk 64]
    __shared__ __align__(16) float gvs[H2];
    __shared__ int lbuf[512];
    __shared__ int lcnt;
    int bid = blockIdx.x;            // b(2) x it(32) x jt(16)
    int b  = bid >> 9;
    int i0 = ((bid >> 4) & 31) * 16;
    int j0 = (bid & 15) * 32;
    int t = threadIdx.x;
    gvs[t] = W2[t * 2 + 1] - W2[t * 2];
    if (t == 0) lcnt = 0;
    float bias = b2[1] - b2[0];
    int ti = t >> 4, tj = t & 15;    // i = i0+ti; j in {j0+tj, j0+tj+16}
    float acc0 = 0.f, acc1 = 0.f;
    for (int gc = 0; gc < H2; gc += 64) {
        __syncthreads();
        {   // stage U: 16 rows x 16 float4, 1/thread, coalesced
            int ui = t >> 4, gq = t & 15;
            *(float4*)&Us[ui][gq * 4] =
                *(const float4*)(U32 + ((size_t)(b * LQ) + i0 + ui) * H2 + gc + gq * 4);
        }
        {   // stage W: 32 rows x 16 float4, 2/thread, coalesced
            int wj = t >> 3, gq = t & 7;
            const float* src = W32 + ((size_t)(b * LQ) + j0 + wj) * H2 + gc;
            *(float4*)&Ws[wj][gq * 4] = *(const float4*)(src + gq * 4);
            *(float4*)&Ws[wj][(gq + 8) * 4] = *(const float4*)(src + (gq + 8) * 4);
        }
        __syncthreads();
        float4 u_c  = *(const float4*)&Us[ti][0];
        float4 gv_c = *(const float4*)&gvs[gc];
        float4 wA_c = *(const float4*)&Ws[tj][0];
        float4 wB_c = *(const float4*)&Ws[tj + 16][0];
#pragma unroll 5
        for (int gg = 0; gg < 60; gg += 4) {
            float4 u_n  = *(const float4*)&Us[ti][gg + 4];
            float4 gv_n = *(const float4*)&gvs[gc + gg + 4];
            float4 wA_n = *(const float4*)&Ws[tj][gg + 4];
            float4 wB_n = *(const float4*)&Ws[tj + 16][gg + 4];
            acc0 = fmaf(fmaxf(u_c.x + wA_c.x, 0.f), gv_c.x, acc0);
            acc1 = fmaf(fmaxf(u_c.x + wB_c.x, 0.f), gv_c.x, acc1);
            acc0 = fmaf(fmaxf(u_c.y + wA_c.y, 0.f), gv_c.y, acc0);
            acc1 = fmaf(fmaxf(u_c.y + wB_c.y, 0.f), gv_c.y, acc1);
            acc0 = fmaf(fmaxf(u_c.z + wA_c.z, 0.f), gv_c.z, acc0);
            acc1 = fmaf(fmaxf(u_c.z + wB_c.z, 0.f), gv_c.z, acc1);
            acc0 = fmaf(fmaxf(u_c.w + wA_c.w, 0.f), gv_c.w, acc0);
            acc1 = fmaf(fmaxf(u_c.w + wB_c.w, 0.f), gv_c.w, acc1);
            u_c = u_n; gv_c = gv_n; wA_c = wA_n; wB_c = wB_n;
        }
        acc0 = fmaf(fmaxf(u_c.x + wA_c.x, 0.f), gv_c.x, acc0);
        acc1 = fmaf(fmaxf(u_c.x + wB_c.x, 0.f), gv_c.x, acc1);
        acc0 = fmaf(fmaxf(u_c.y + wA_c.y, 0.f), gv_c.y, acc0);
        acc1 = fmaf(fmaxf(u_c.y + wB_c.y, 0.f), gv_c.y, acc1);
        acc0 = fmaf(fmaxf(u_c.z + wA_c.z, 0.f), gv_c.z, acc0);
        acc1 = fmaf(fmaxf(u_c.z + wB_c.z, 0.f), gv_c.z, acc1);
        acc0 = fmaf(fmaxf(u_c.w + wA_c.w, 0.f), gv_c.w, acc0);
        acc1 = fmaf(fmaxf(u_c.w + wB_c.w, 0.f), gv_c.w, acc1);
    }
    int row = b * LQ + i0 + ti;
    float gA = acc0 + bias, gB = acc1 + bias;
    int jA = j0 + tj, jB = j0 + tj + 16;
    dec_out[(size_t)row * LQ + jA] = gA > 0.f ? 1.f : 0.f;
    dec_out[(size_t)row * LQ + jB] = gB > 0.f ? 1.f : 0.f;
    if (fabsf(gA) < 2e-2f) { int lx = atomicAdd(&lcnt, 1); lbuf[lx] = (row << 9) | jA; }
    if (fabsf(gB) < 2e-2f) { int lx = atomicAdd(&lcnt, 1); lbuf[lx] = (row << 9) | jB; }
    __syncthreads();
    // ---- in-block fp64 re-eval (gap64's exact math/order), wave per pair ----
    int nloc = lcnt;
    int wv = t >> 6, ln = t & 63;
    for (int x = wv; x < nloc; x += 4) {
        int pij = lbuf[x];
        int j = pij & (LQ - 1);
        int prow = pij >> 9;
        int pb = prow >> 9;
        const double* u = U64 + (size_t)prow * H2;
        const double* w = W64 + ((size_t)(pb * LQ) + j) * H2;
        double acc = 0.0;
        for (int g = ln; g < H2; g += 64) {
            double tv = u[g] + w[g];
            tv = tv > 0.0 ? tv : 0.0;
            acc = fma(tv, (double)W2[g * 2 + 1] - (double)W2[g * 2 + 0], acc);
        }
#pragma unroll
        for (int off = 32; off; off >>= 1) acc += __shfl_xor(acc, off, 64);
        if (ln == 0) {
            acc += (double)b2[1] - (double)b2[0];
            dec_out[(size_t)prow * LQ + j] = acc > 0.0 ? 1.f : 0.f;
        }
    }
}

// ---------------------------------------------------------------------------
// Fused attention v2 (proven R4, 55.4 us): grid 512 (32 bn x 16 i-tiles of
// 32 rows). QK 4i x 4j microtile; softmax width-32 shuffles; PV per 64-j
// chunk via Ps[32][65] (broadcast) + Vs[64][68] (2-way, free).
// R8's PV-v5 rewrite REVERTED: its Vs stride-72 layout aliased all four
// j-quarters to the same banks (conflicts 1.47M -> 4.03M) and VGPR 140.
// ---------------------------------------------------------------------------
__global__ __launch_bounds__(256) void fused_attn(
    const float* __restrict__ q, const float* __restrict__ k,
    const float* __restrict__ v, const float* __restrict__ dec,
    float* __restrict__ attn, float* __restrict__ out)
{
    __shared__ __align__(16) float smem[10752];   // 43 KB, phase-overlaid
    float* qT = smem;            // [64][36]   kk-major
    float* kT = smem + 2304;     // [64][132]  kk-major
    float* Ps = smem;            // [32][65]   i-major  (PV phase)
    float* Vs = smem + 2112;     // [64][68]   j-major  (PV phase)
    int bid = blockIdx.x;
    int bn = bid >> 4;
    int i0 = (bid & 15) * 32;
    int b = bn >> 4;
    int t = threadIdx.x;

    {   // stage qT (transpose): i = t>>3, kkq = (t&7)+8*it
        int qi = t >> 3;
        const float* src = q + ((size_t)bn * LQ + i0 + qi) * DKk;
#pragma unroll
        for (int it = 0; it < 2; ++it) {
            int kkq = (t & 7) + it * 8;
            float4 t4 = *(const float4*)(src + kkq * 4);
            qT[(kkq * 4 + 0) * 36 + qi] = t4.x;
            qT[(kkq * 4 + 1) * 36 + qi] = t4.y;
            qT[(kkq * 4 + 2) * 36 + qi] = t4.z;
            qT[(kkq * 4 + 3) * 36 + qi] = t4.w;
        }
    }
    int tiq = t >> 5;            // 0..7  -> i = tiq*4 + r
    int tjq = t & 31;            // 0..31 -> j = c*128 + tjq*4 + cc
    float s[4][4][4];

#pragma unroll
    for (int c = 0; c < 4; ++c) {
        __syncthreads();
        {   // stage kT (transpose): j = (t>>2)+(it&1)*64, kkq = (t&3)+(it>>1)*4
            int kj = t >> 2;
#pragma unroll
            for (int it = 0; it < 8; ++it) {
                int jj = kj + (it & 1) * 64;
                int kkq = (t & 3) + (it >> 1) * 4;
                float4 t4 = *(const float4*)(k + ((size_t)bn * LQ + c * 128 + jj) * DKk + kkq * 4);
                kT[(kkq * 4 + 0) * 132 + jj] = t4.x;
                kT[(kkq * 4 + 1) * 132 + jj] = t4.y;
                kT[(kkq * 4 + 2) * 132 + jj] = t4.z;
                kT[(kkq * 4 + 3) * 132 + jj] = t4.w;
            }
        }
        __syncthreads();
        float acc[4][4] = {};
#pragma unroll 8
        for (int kk = 0; kk < 64; ++kk) {
            float4 a  = *(const float4*)&qT[kk * 36 + tiq * 4];
            float4 bb = *(const float4*)&kT[kk * 132 + tjq * 4];
            acc[0][0] = fmaf(a.x, bb.x, acc[0][0]); acc[0][1] = fmaf(a.x, bb.y, acc[0][1]);
            acc[0][2] = fmaf(a.x, bb.z, acc[0][2]); acc[0][3] = fmaf(a.x, bb.w, acc[0][3]);
            acc[1][0] = fmaf(a.y, bb.x, acc[1][0]); acc[1][1] = fmaf(a.y, bb.y, acc[1][1]);
            acc[1][2] = fmaf(a.y, bb.z, acc[1][2]); acc[1][3] = fmaf(a.y, bb.w, acc[1][3]);
            acc[2][0] = fmaf(a.z, bb.x, acc[2][0]); acc[2][1] = fmaf(a.z, bb.y, acc[2][1]);
            acc[2][2] = fmaf(a.z, bb.z, acc[2][2]); acc[2][3] = fmaf(a.z, bb.w, acc[2][3]);
            acc[3][0] = fmaf(a.w, bb.x, acc[3][0]); acc[3][1] = fmaf(a.w, bb.y, acc[3][1]);
            acc[3][2] = fmaf(a.w, bb.z, acc[3][2]); acc[3][3] = fmaf(a.w, bb.w, acc[3][3]);
        }
#pragma unroll
        for (int r = 0; r < 4; ++r) {
            float4 m4 = *(const float4*)&dec[((size_t)(b * LQ) + i0 + tiq * 4 + r) * LQ + c * 128 + tjq * 4];
            s[c][r][0] = m4.x != 0.f ? acc[r][0] * 0.125f : NEG_INF;
            s[c][r][1] = m4.y != 0.f ? acc[r][1] * 0.125f : NEG_INF;
            s[c][r][2] = m4.z != 0.f ? acc[r][2] * 0.125f : NEG_INF;
            s[c][r][3] = m4.w != 0.f ? acc[r][3] * 0.125f : NEG_INF;
        }
    }
    // softmax over 512 j per row (width-32 shuffle groups = tjq)
#pragma unroll
    for (int r = 0; r < 4; ++r) {
        float m = NEG_INF;
#pragma unroll
        for (int c = 0; c < 4; ++c)
#pragma unroll
            for (int cc = 0; cc < 4; ++cc) m = fmaxf(m, s[c][r][cc]);
#pragma unroll
        for (int off = 1; off < 32; off <<= 1) m = fmaxf(m, __shfl_xor(m, off, 32));
        float sum = 0.f;
#pragma unroll
        for (int c = 0; c < 4; ++c)
#pragma unroll
            for (int cc = 0; cc < 4; ++cc) {
                float e = __expf(s[c][r][cc] - m);
                s[c][r][cc] = e; sum += e;
            }
#pragma unroll
        for (int off = 1; off < 32; off <<= 1) sum += __shfl_xor(sum, off, 32);
        float inv = 1.f / sum;
#pragma unroll
        for (int c = 0; c < 4; ++c)
#pragma unroll
            for (int cc = 0; cc < 4; ++cc) s[c][r][cc] *= inv;
    }
#pragma unroll
    for (int c = 0; c < 4; ++c)
#pragma unroll
        for (int r = 0; r < 4; ++r) {
            float4 wv = make_float4(s[c][r][0], s[c][r][1], s[c][r][2], s[c][r][3]);
            *(float4*)&attn[((size_t)bn * LQ + i0 + tiq * 4 + r) * LQ + c * 128 + tjq * 4] = wv;
        }
    // ---- PV over eight 64-j chunks ----
    int tio = t >> 4;            // 0..15 -> i = tio*2 + rr
    int tdo = t & 15;            // 0..15 -> d = tdo*4
    float o[2][4] = {};
#pragma unroll
    for (int c8 = 0; c8 < 8; ++c8) {
        __syncthreads();
        if ((tjq >> 4) == (c8 & 1)) {      // this thread's s covers this chunk
            int jl4 = tjq & 15;
            int c = c8 >> 1;
#pragma unroll
            for (int r = 0; r < 4; ++r)
#pragma unroll
                for (int cc = 0; cc < 4; ++cc)
                    Ps[(tiq * 4 + r) * 65 + jl4 * 4 + cc] = s[c][r][cc];
        }
        {   // stage Vs: j = t>>2, dq = (t&3)+4*it
            int vj = t >> 2;
#pragma unroll
            for (int it = 0; it < 4; ++it) {
                int dq = (t & 3) + it * 4;
                *(float4*)&Vs[vj * 68 + dq * 4] =
                    *(const float4*)(v + ((size_t)bn * LQ + c8 * 64 + vj) * DVv + dq * 4);
            }
        }
        __syncthreads();
#pragma unroll 8
        for (int jj = 0; jj < 64; ++jj) {
            float p0 = Ps[(tio * 2 + 0) * 65 + jj];
            float p1 = Ps[(tio * 2 + 1) * 65 + jj];
            float4 v4 = *(const float4*)&Vs[jj * 68 + tdo * 4];
            o[0][0] = fmaf(p0, v4.x, o[0][0]); o[0][1] = fmaf(p0, v4.y, o[0][1]);
            o[0][2] = fmaf(p0, v4.z, o[0][2]); o[0][3] = fmaf(p0, v4.w, o[0][3]);
            o[1][0] = fmaf(p1, v4.x, o[1][0]); o[1][1] = fmaf(p1, v4.y, o[1][1]);
            o[1][2] = fmaf(p1, v4.z, o[1][2]); o[1][3] = fmaf(p1, v4.w, o[1][3]);
        }
    }
#pragma unroll
    for (int rr = 0; rr < 2; ++rr)
        *(float4*)&out[((size_t)bn * LQ + i0 + tio * 2 + rr) * DVv + tdo * 4] =
            make_float4(o[rr][0], o[rr][1], o[rr][2], o[rr][3]);
}

// ---------------------------------------------------------------------------
extern "C" void kernel_launch(void* const* d_in, const int* in_sizes, int n_in,
                              void* d_out, int out_size, void* d_ws, size_t ws_size,
                              hipStream_t stream)
{
    const float* q  = (const float*)d_in[0];
    const float* k  = (const float*)d_in[1];
    const float* v  = (const float*)d_in[2];
    const float* d0 = (const float*)d_in[3];
    const float* d1 = (const float*)d_in[4];
    const float* W1 = (const float*)d_in[5];
    const float* b1 = (const float*)d_in[6];
    const float* W2 = (const float*)d_in[7];
    const float* b2 = (const float*)d_in[8];

    float* out  = (float*)d_out;                                  // [2,16,512,64]
    float* attn = out + (size_t)BB * NN * LQ * DVv;               // [2,16,512,512]
    float* dec  = attn + (size_t)BB * NN * LQ * LQ;               // [2,1,512,512]

    // Scratch inside the attn region (32 MB); fully consumed before
    // fused_attn overwrites every attn element (same stream => ordered).
    char* scratch = (char*)attn;
    double* U64 = (double*)(scratch);                             // 0..2 MB
    double* W64 = (double*)(scratch + (2u << 20));                // 2..4 MB
    float*  U32 = (float*) (scratch + (4u << 20));                // 4..5 MB
    float*  W32 = (float*) (scratch + (5u << 20));                // 5..6 MB

    mlp_stage1<<<1024, 256, 0, stream>>>(d0, d1, W1, b1, U64, W64, U32, W32);
    dec_full<<<1024, 256, 0, stream>>>(U32, W32, U64, W64, W2, b2, dec);
    fused_attn<<<512, 256, 0, stream>>>(q, k, v, dec, attn, out);
}